// Round 4
// baseline (251.895 us; speedup 1.0000x reference)
//
#include <hip/hip_runtime.h>
#include <hip/hip_bf16.h>
#include <math.h>
#include <stdint.h>

// Problem constants (B,S,H) = (8,128,768)
#define S_LEN 128
#define H_DIM 768
#define B_DIM 8
#define NPAIR 8256          // S*(S+1)/2
#define MROWS 1024          // B*S
#define NTOT  3072          // 4*H : [Ax | Bx | Gx | Ay]
#define EPSC  1e-12f

typedef __bf16 bf16x8 __attribute__((ext_vector_type(8)));
typedef float  f32x4  __attribute__((ext_vector_type(4)));

// RNE float -> bf16 (inputs finite)
static __device__ __forceinline__ unsigned short f2bf(float f) {
  union { float f; unsigned u; } a; a.f = f;
  unsigned u = a.u;
  u += 0x7fffu + ((u >> 16) & 1u);
  return (unsigned short)(u >> 16);
}

// -------------------- prep --------------------
// blocks 0..1023          : convert x,y row -> bf16; stats on y; CY=(y-m)*inv fp32
// blocks 1024..1024+2303  : pack weights Wb[3072][768] bf16
__global__ __launch_bounds__(256) void prep(const float* __restrict__ x,
                                            const float* __restrict__ y,
                                            const float* __restrict__ catW,
                                            const float* __restrict__ betaW,
                                            const float* __restrict__ gammaW,
                                            unsigned short* __restrict__ Xb,
                                            unsigned short* __restrict__ Yb,
                                            unsigned short* __restrict__ Wb,
                                            float* __restrict__ CY) {
  const int bid = blockIdx.x;
  const int tid = threadIdx.x;
  if (bid < MROWS) {
    const int row = bid;
    float s = 0.f, s2 = 0.f;
    float4 vy = make_float4(0.f, 0.f, 0.f, 0.f);
    if (tid < 192) {
      const int o = tid * 4;
      float4 vx = *(const float4*)(x + (size_t)row * H_DIM + o);
      vy = *(const float4*)(y + (size_t)row * H_DIM + o);
      ushort4 ox; ox.x = f2bf(vx.x); ox.y = f2bf(vx.y); ox.z = f2bf(vx.z); ox.w = f2bf(vx.w);
      ushort4 oy; oy.x = f2bf(vy.x); oy.y = f2bf(vy.y); oy.z = f2bf(vy.z); oy.w = f2bf(vy.w);
      *(ushort4*)(Xb + (size_t)row * H_DIM + o) = ox;
      *(ushort4*)(Yb + (size_t)row * H_DIM + o) = oy;
      s  = vy.x + vy.y + vy.z + vy.w;
      s2 = vy.x * vy.x + vy.y * vy.y + vy.z * vy.z + vy.w * vy.w;
    }
    for (int off = 32; off > 0; off >>= 1) { s += __shfl_down(s, off); s2 += __shfl_down(s2, off); }
    __shared__ float ls[4], ls2[4], smv[2];
    if ((tid & 63) == 0) { ls[tid >> 6] = s; ls2[tid >> 6] = s2; }
    __syncthreads();
    if (tid == 0) {
      float S1 = ls[0] + ls[1] + ls[2] + ls[3];
      float S2 = ls2[0] + ls2[1] + ls2[2] + ls2[3];
      float m = S1 / H_DIM;
      float var = S2 / H_DIM - m * m;
      float st = var + EPSC;                 // reference: std = (var+eps)**2
      smv[0] = m;
      smv[1] = 1.0f / (st * st);
    }
    __syncthreads();
    if (tid < 192) {
      const int o = tid * 4;
      const float m = smv[0], iv = smv[1];
      float4 cy;
      cy.x = (vy.x - m) * iv; cy.y = (vy.y - m) * iv;
      cy.z = (vy.z - m) * iv; cy.w = (vy.w - m) * iv;
      *(float4*)(CY + (size_t)row * H_DIM + o) = cy;
    }
  } else {
    int idx = (bid - MROWS) * 256 + tid;     // one float4 per thread
    int e = idx * 4;
    int n = e / H_DIM, k = e % H_DIM;
    const float* src;
    if      (n < 768)  src = catW   + (size_t)n * 1536 + k;
    else if (n < 1536) src = betaW  + (size_t)(n - 768) * 768 + k;
    else if (n < 2304) src = gammaW + (size_t)(n - 1536) * 768 + k;
    else               src = catW   + (size_t)(n - 2304) * 1536 + 768 + k;
    float4 v = *(const float4*)src;
    ushort4 o; o.x = f2bf(v.x); o.y = f2bf(v.y); o.z = f2bf(v.z); o.w = f2bf(v.w);
    *(ushort4*)(Wb + e) = o;
  }
}

// -------------------- MFMA GEMM 64x64 tiles: P[m][n] fp32 --------------------
__device__ __forceinline__ void gload_lds16(const void* g, void* l) {
  __builtin_amdgcn_global_load_lds(
      (const __attribute__((address_space(1))) unsigned int*)(uintptr_t)g,
      (__attribute__((address_space(3))) unsigned int*)(uintptr_t)l,
      16, 0, 0);
}

__global__ __launch_bounds__(256) void gemm_bt(const unsigned short* __restrict__ Xb,
                                               const unsigned short* __restrict__ Yb,
                                               const unsigned short* __restrict__ Wb,
                                               float* __restrict__ P) {
  __shared__ unsigned short As[64 * 32];   // [m][k], k contiguous
  __shared__ unsigned short Bs[64 * 32];   // [n][k]
  const int m0 = blockIdx.x * 64;
  const int n0 = blockIdx.y * 64;
  const unsigned short* A = (n0 < 2304) ? Xb : Yb;
  const unsigned short* Arow = A + (size_t)m0 * H_DIM;
  const unsigned short* Brow = Wb + (size_t)n0 * H_DIM;

  const int tid  = threadIdx.x;
  const int lane = tid & 63;
  const int wave = tid >> 6;
  const int wm = (wave >> 1) * 32;
  const int wn = (wave & 1) * 32;
  const int quad = lane >> 4;
  const int r    = lane & 15;

  const int ar = tid >> 2;          // staging row 0..63
  const int ac = (tid & 3) * 8;     // staging col {0,8,16,24}

  f32x4 acc[2][2] = {};

  for (int k0 = 0; k0 < H_DIM; k0 += 32) {
    gload_lds16(Arow + (size_t)ar * H_DIM + k0 + ac, &As[tid * 8]);
    gload_lds16(Brow + (size_t)ar * H_DIM + k0 + ac, &Bs[tid * 8]);
    __syncthreads();

    bf16x8 af[2], bfr[2];
#pragma unroll
    for (int mi = 0; mi < 2; ++mi)
      af[mi] = *(const bf16x8*)&As[(wm + mi * 16 + r) * 32 + quad * 8];
#pragma unroll
    for (int ni = 0; ni < 2; ++ni)
      bfr[ni] = *(const bf16x8*)&Bs[(wn + ni * 16 + r) * 32 + quad * 8];
#pragma unroll
    for (int mi = 0; mi < 2; ++mi)
#pragma unroll
      for (int ni = 0; ni < 2; ++ni)
        acc[mi][ni] = __builtin_amdgcn_mfma_f32_16x16x32_bf16(af[mi], bfr[ni], acc[mi][ni], 0, 0, 0);
    __syncthreads();
  }

#pragma unroll
  for (int mi = 0; mi < 2; ++mi) {
#pragma unroll
    for (int ni = 0; ni < 2; ++ni) {
      const int row = m0 + wm + mi * 16 + quad * 4;   // C/D: col=lane&15, row=quad*4+reg
      const int col = n0 + wn + ni * 16 + r;
#pragma unroll
      for (int reg = 0; reg < 4; ++reg)
        P[(size_t)(row + reg) * NTOT + col] = acc[mi][ni][reg];
    }
  }
}

// -------------------- epilogue --------------------
// 1024 blocks: b = blockIdx.x % 8 (XCD locality), q = blockIdx.x / 8 (0..127)
// ii = q>>1, half = q&1. Block covers half of the 129 pairs of {i=ii, i=127-ii}.
__global__ __launch_bounds__(192) void epilogue(const float* __restrict__ P,
                                                const float* __restrict__ CY,
                                                const float* __restrict__ cat_b,
                                                const float* __restrict__ beta,
                                                const float* __restrict__ gamma,
                                                float* __restrict__ out) {
  const int b    = blockIdx.x & 7;
  const int q    = blockIdx.x >> 3;
  const int ii   = q >> 1;
  const int half = q & 1;
  const int i1 = ii, i2 = 127 - ii;
  const int n1 = 128 - i1;              // pairs under i1 (>= 65 for ii<=63)
  const int t0 = half ? 65 : 0;
  const int t1 = half ? 129 : 65;
  const int o  = threadIdx.x * 4;

  float4 cb = *(const float4*)(cat_b + o);
  float4 be = *(const float4*)(beta + o);
  float4 ga = *(const float4*)(gamma + o);

  int icur = -1;
  float4 ax, bx, gx;
  ax = bx = gx = make_float4(0.f, 0.f, 0.f, 0.f);
  for (int t = t0; t < t1; ++t) {
    int i, j, p;
    if (t < n1) { i = i1; j = i1 + t;       p = i1 * (257 - i1) / 2 + t; }
    else        { int tt = t - n1; i = i2; j = i2 + tt; p = i2 * (257 - i2) / 2 + tt; }
    if (i != icur) {
      icur = i;
      const float* ri = P + (size_t)(b * S_LEN + i) * NTOT;
      ax = *(const float4*)(ri + o);
      bx = *(const float4*)(ri + 768 + o);
      gx = *(const float4*)(ri + 1536 + o);
    }
    const int rowj = b * S_LEN + j;
    float4 ay = *(const float4*)(P + (size_t)rowj * NTOT + 2304 + o);
    float4 cy = *(const float4*)(CY + (size_t)rowj * H_DIM + o);
    f32x4 rr;
    rr[0] = 0.5f * (fmaxf(ax.x + ay.x + cb.x, 0.f) + cy.x * (gx.x + ga.x) + bx.x + be.x);
    rr[1] = 0.5f * (fmaxf(ax.y + ay.y + cb.y, 0.f) + cy.y * (gx.y + ga.y) + bx.y + be.y);
    rr[2] = 0.5f * (fmaxf(ax.z + ay.z + cb.z, 0.f) + cy.z * (gx.z + ga.z) + bx.z + be.z);
    rr[3] = 0.5f * (fmaxf(ax.w + ay.w + cb.w, 0.f) + cy.w * (gx.w + ga.w) + bx.w + be.w);
    __builtin_nontemporal_store(rr, (f32x4*)(out + ((size_t)b * NPAIR + p) * H_DIM + o));
  }
}

extern "C" void kernel_launch(void* const* d_in, const int* in_sizes, int n_in,
                              void* d_out, int out_size, void* d_ws, size_t ws_size,
                              hipStream_t stream) {
  const float* x      = (const float*)d_in[0];  // (8,128,768)
  const float* y      = (const float*)d_in[1];  // (8,128,768)
  const float* catW   = (const float*)d_in[2];  // (768,1536)
  const float* catb   = (const float*)d_in[3];  // (768,)
  const float* beta   = (const float*)d_in[4];  // (768,)
  const float* gamma  = (const float*)d_in[5];  // (768,)
  const float* betaW  = (const float*)d_in[6];  // (768,768)
  const float* gammaW = (const float*)d_in[7];  // (768,768)

  // workspace layout (~23.6 MB total)
  char* ws = (char*)d_ws;
  unsigned short* Xb = (unsigned short*)(ws);              // 1.5 MB
  unsigned short* Yb = (unsigned short*)(ws + 1572864);    // 1.5 MB
  unsigned short* Wb = (unsigned short*)(ws + 3145728);    // 4.5 MB
  float*          P  = (float*)(ws + 7864320);             // 1024*3072*4 = 12.6 MB
  float*          CY = (float*)(ws + 20447232);            // 1024*768*4 = 3.15 MB
  float*          out = (float*)d_out;                     // (8,8256,768) fp32

  prep<<<MROWS + 2304, 256, 0, stream>>>(x, y, catW, betaW, gammaW, Xb, Yb, Wb, CY);
  gemm_bt<<<dim3(16, 48), 256, 0, stream>>>(Xb, Yb, Wb, P);
  epilogue<<<1024, 192, 0, stream>>>(P, CY, catb, beta, gamma, out);
}